// Round 10
// baseline (960.842 us; speedup 1.0000x reference)
//
#include <hip/hip_runtime.h>
#include <hip/hip_bf16.h>

#define D 128

typedef __bf16 bf16x8 __attribute__((ext_vector_type(8)));
typedef float  f32x4  __attribute__((ext_vector_type(4)));

// ---------------- batched CSR build (both graphs; graph-1 node ids offset +n0) ----------------

__global__ void k_count_deg2(const int* __restrict__ ei, const int* __restrict__ eia,
                             int* __restrict__ deg, int e0, int e1, int n0) {
    int i = blockIdx.x * blockDim.x + threadIdx.x;
    if (i < e0) atomicAdd(&deg[ei[e0 + i]], 1);
    else if (i < e0 + e1) { int k = i - e0; atomicAdd(&deg[eia[e1 + k] + n0], 1); }
}

__global__ void k_dis(const int* __restrict__ deg, float* __restrict__ dis, int n) {
    int i = blockIdx.x * blockDim.x + threadIdx.x;
    if (i < n) dis[i] = rsqrtf((float)deg[i] + 1.0f);
}

__global__ __launch_bounds__(256) void k_scan1(const int* __restrict__ deg,
                                               int* __restrict__ rowptr,
                                               int* __restrict__ bsum, int n) {
    __shared__ int tmp[256];
    int t = threadIdx.x;
    int i = blockIdx.x * 256 + t;
    tmp[t] = (i < n) ? deg[i] : 0;
    __syncthreads();
    for (int ofs = 1; ofs < 256; ofs <<= 1) {
        int add = (t >= ofs) ? tmp[t - ofs] : 0;
        __syncthreads();
        tmp[t] += add;
        __syncthreads();
    }
    if (i < n) rowptr[i + 1] = tmp[t];
    if (t == 255) bsum[blockIdx.x] = tmp[255];
}

// single-block sequential-chunk scan: handles nb up to anything (nb=391 here)
__global__ __launch_bounds__(256) void k_scan2(int* __restrict__ bsum, int nb) {
    __shared__ int tmp[256];
    int t = threadIdx.x;
    int carry = 0;
    for (int base = 0; base < nb; base += 256) {
        int idx = base + t;
        tmp[t] = (idx < nb) ? bsum[idx] : 0;
        __syncthreads();
        for (int ofs = 1; ofs < 256; ofs <<= 1) {
            int add = (t >= ofs) ? tmp[t - ofs] : 0;
            __syncthreads();
            tmp[t] += add;
            __syncthreads();
        }
        if (idx < nb) bsum[idx] = tmp[t] + carry;
        int total = tmp[255];
        __syncthreads();
        carry += total;
    }
}

// finalize rowptr and init cursor = rowptr (fused)
__global__ void k_scan3(int* __restrict__ rowptr, int* __restrict__ cursor,
                        const int* __restrict__ bsum, int n) {
    int i = blockIdx.x * blockDim.x + threadIdx.x;
    if (i == 0) { rowptr[0] = 0; cursor[0] = 0; }
    if (i < n) {
        int b = i >> 8;
        int val = rowptr[i + 1];
        if (b > 0) val += bsum[b - 1];
        rowptr[i + 1] = val;
        if (i + 1 < n) cursor[i + 1] = val;
    }
}

// scatter both graphs' edges; payload = raw per-graph src id
__global__ void k_csr_fill2(const int* __restrict__ ei, const int* __restrict__ eia,
                            int* __restrict__ cursor, int* __restrict__ csr_src,
                            int e0, int e1, int n0) {
    int i = blockIdx.x * blockDim.x + threadIdx.x;
    int s, d;
    if (i < e0) { s = ei[i]; d = ei[e0 + i]; }
    else if (i < e0 + e1) { int k = i - e0; s = eia[k]; d = eia[e1 + k] + n0; }
    else return;
    int pos = atomicAdd(&cursor[d], 1);
    csr_src[pos] = s;
}

// ---------------- weight packing: f32 W[128][128] -> per-lane MFMA frag order ----------------
// slot i = ((kb*8 + ct)*64 + lane)*8 + j  ->  W[kb*32 + (lane>>4)*8 + j][ct*16 + (lane&15)]

__global__ __launch_bounds__(256) void k_pack_w5(
    const float* __restrict__ w0, const float* __restrict__ w1,
    const float* __restrict__ w2, const float* __restrict__ w3,
    const float* __restrict__ w4, __bf16* __restrict__ out) {
    int q = blockIdx.x >> 6;
    const float* W = (q == 0) ? w0 : (q == 1) ? w1 : (q == 2) ? w2 : (q == 3) ? w3 : w4;
    int i = ((blockIdx.x & 63) << 8) | threadIdx.x;      // 0..16383
    int j    = i & 7;
    int lane = (i >> 3) & 63;
    int ct   = (i >> 9) & 7;
    int kb   = i >> 12;
    int k = kb * 32 + (lane >> 4) * 8 + j;
    int c = ct * 16 + (lane & 15);
    float w = W[k * D + c];
    __bf16 hi = (__bf16)w;
    __bf16 lo = (__bf16)(w - (float)hi);
    __bf16* dstp = out + (size_t)q * 32768;
    dstp[i] = hi;
    dstp[16384 + i] = lo;
}

// ---------------- split-bf16 MFMA GEMM: C[n,128] = A[n,128] @ W + (bias)(relu) ----------------
// 256 thr = 4 waves; wave computes 16 rows x 128 cols; 64 rows/block.

__global__ __launch_bounds__(256) void k_gemm_mfma(
    const float* __restrict__ A, const __bf16* __restrict__ Wp,
    const float* __restrict__ bias, float* __restrict__ C, int n,
    int fuse_bias, int fuse_relu) {
    __shared__ __bf16 Ws[32768];     // 64 KiB: hi | lo, frag-packed
    int t = threadIdx.x;
    for (int i = t * 8; i < 32768; i += 2048)
        *(float4*)&Ws[i] = *(const float4*)&Wp[i];

    int wv = t >> 6, lane = t & 63;
    int lrow = lane & 15, lhi = lane >> 4;
    int m0 = blockIdx.x * 64 + wv * 16;

    bf16x8 ahi[4], alo[4];
    int arow = m0 + lrow;
    const float* ap = A + (size_t)arow * D + lhi * 8;
    #pragma unroll
    for (int kb = 0; kb < 4; ++kb) {
        float av[8];
        if (arow < n) {
            float4 p0 = *(const float4*)(ap + kb * 32);
            float4 p1 = *(const float4*)(ap + kb * 32 + 4);
            av[0] = p0.x; av[1] = p0.y; av[2] = p0.z; av[3] = p0.w;
            av[4] = p1.x; av[5] = p1.y; av[6] = p1.z; av[7] = p1.w;
        } else {
            #pragma unroll
            for (int j = 0; j < 8; ++j) av[j] = 0.0f;
        }
        #pragma unroll
        for (int j = 0; j < 8; ++j) {
            __bf16 h = (__bf16)av[j];
            ahi[kb][j] = h;
            alo[kb][j] = (__bf16)(av[j] - (float)h);
        }
    }
    __syncthreads();

    f32x4 acc[8];
    f32x4 zz = {0.f, 0.f, 0.f, 0.f};
    #pragma unroll
    for (int i = 0; i < 8; ++i) acc[i] = zz;

    #pragma unroll
    for (int kb = 0; kb < 4; ++kb) {
        #pragma unroll
        for (int ct = 0; ct < 8; ++ct) {
            int off = ((kb * 8 + ct) * 64 + lane) * 8;
            bf16x8 bh = *(const bf16x8*)&Ws[off];
            bf16x8 bl = *(const bf16x8*)&Ws[16384 + off];
            acc[ct] = __builtin_amdgcn_mfma_f32_16x16x32_bf16(ahi[kb], bh, acc[ct], 0, 0, 0);
            acc[ct] = __builtin_amdgcn_mfma_f32_16x16x32_bf16(ahi[kb], bl, acc[ct], 0, 0, 0);
            acc[ct] = __builtin_amdgcn_mfma_f32_16x16x32_bf16(alo[kb], bh, acc[ct], 0, 0, 0);
        }
    }

    // C/D layout: col=lane&15, row=(lane>>4)*4+reg  [verified m89/m91]
    #pragma unroll
    for (int ct = 0; ct < 8; ++ct) {
        int col = ct * 16 + lrow;
        float bv = fuse_bias ? bias[col] : 0.0f;
        #pragma unroll
        for (int r = 0; r < 4; ++r) {
            int row = m0 + lhi * 4 + r;
            if (row < n) {
                float v = acc[ct][r] + bv;
                if (fuse_relu) v = fmaxf(v, 0.0f);
                C[(size_t)row * D + col] = v;
            }
        }
    }
}

// ---------------- GCN aggregation: 2 waves per node, 64 ch/wave, unroll 8 ----------------

__global__ __launch_bounds__(256) void k_csr_agg2(
    const float* __restrict__ H, const int* __restrict__ rowptr,
    const int* __restrict__ csr_src, const float* __restrict__ dis,
    const float* __restrict__ bias, float* __restrict__ X, int n, int relu) {
    int wid = (blockIdx.x * 256 + threadIdx.x) >> 6;
    int lane = threadIdx.x & 63;
    int w = __builtin_amdgcn_readfirstlane(wid);   // wave-uniform
    int v = w >> 1;
    int half = w & 1;
    if (v >= n) return;
    int ch = half * 64 + lane;
    float dv = dis[v];
    float acc = H[(size_t)v * D + ch] * dv * dv;
    int beg = rowptr[v], end = rowptr[v + 1];
    int j = beg;
    for (; j + 8 <= end; j += 8) {
        int s[8]; float ww[8]; float a[8];
        #pragma unroll
        for (int q = 0; q < 8; ++q) s[q] = csr_src[j + q];
        #pragma unroll
        for (int q = 0; q < 8; ++q) ww[q] = dis[s[q]] * dv;
        #pragma unroll
        for (int q = 0; q < 8; ++q) a[q] = H[(size_t)s[q] * D + ch];
        #pragma unroll
        for (int q = 0; q < 8; ++q) acc = fmaf(a[q], ww[q], acc);
    }
    for (; j < end; ++j) {
        int s = csr_src[j];
        acc = fmaf(H[(size_t)s * D + ch], dis[s] * dv, acc);
    }
    acc += bias[ch];
    if (relu) acc = fmaxf(acc, 0.f);
    X[(size_t)v * D + ch] = acc;
}

// ---------------- launcher ----------------

extern "C" void kernel_launch(void* const* d_in, const int* in_sizes, int n_in,
                              void* d_out, int out_size, void* d_ws, size_t ws_size,
                              hipStream_t stream) {
    const float* x    = (const float*)d_in[0];
    const int*   ei   = (const int*)d_in[1];
    const float* xa   = (const float*)d_in[2];
    const int*   eia  = (const int*)d_in[3];
    const float* W_in = (const float*)d_in[4];
    const float* b_in = (const float*)d_in[5];
    const float* W_h  = (const float*)d_in[6];
    const float* b_h  = (const float*)d_in[7];
    const float* W_out= (const float*)d_in[8];
    const float* b_out= (const float*)d_in[9];
    const float* Wf1  = (const float*)d_in[10];
    const float* bf1  = (const float*)d_in[11];
    const float* Wf2  = (const float*)d_in[12];
    const float* bf2  = (const float*)d_in[13];

    const int n0 = in_sizes[0] / D;       // 50000
    const int e0 = in_sizes[1] / 2;       // 800000
    const int n1 = in_sizes[2] / D;
    const int e1 = in_sizes[3] / 2;
    const int nt = n0 + n1;               // 100000 total nodes
    const int et = e0 + e1;               // 1.6M total edges

    float* Xf     = (float*)d_ws;                  // [n0,128] per-graph activations
    float* H      = Xf + (size_t)n0 * D;           // [n0,128]
    float* dis    = H  + (size_t)n0 * D;           // [nt]
    int*   deg    = (int*)(dis + nt);              // [nt]
    int*   rowptr = deg + nt;                      // [nt+4]
    int*   cursor = rowptr + (nt + 4);             // [nt]
    int*   bsum   = cursor + nt;                   // [512]
    int*   csrsrc = bsum + 512;                    // [et]
    __bf16* wpack = (__bf16*)(csrsrc + et);        // 5 * 32768 bf16

    float* out = (float*)d_out;

    const float* bl[3] = {b_in, b_h, b_out};

    const int threads = 256;
    const int g_nt   = (nt + threads - 1) / threads;        // 391
    const int g_et   = (et + threads - 1) / threads;
    const int g_gemm = (n0 + 63) / 64;                      // 782
    const int g_agg  = (n0 * 2 * 64 + threads - 1) / threads; // 25000 (2 waves/node)
    const int nb     = g_nt;                                // block sums count

    // pack all 5 weight matrices (hi/lo split, frag order)
    k_pack_w5<<<320, threads, 0, stream>>>(W_in, W_h, W_out, Wf1, Wf2, wpack);

    // ---- batched CSR build over both graphs ----
    hipMemsetAsync(deg, 0, (size_t)nt * sizeof(int), stream);
    k_count_deg2<<<g_et, threads, 0, stream>>>(ei, eia, deg, e0, e1, n0);
    k_dis<<<g_nt, threads, 0, stream>>>(deg, dis, nt);
    k_scan1<<<g_nt, threads, 0, stream>>>(deg, rowptr, bsum, nt);
    k_scan2<<<1, threads, 0, stream>>>(bsum, nb);
    k_scan3<<<g_nt, threads, 0, stream>>>(rowptr, cursor, bsum, nt);
    k_csr_fill2<<<g_et, threads, 0, stream>>>(ei, eia, cursor, csrsrc, e0, e1, n0);

    for (int g = 0; g < 2; ++g) {
        const float* xin   = g ? xa : x;
        const int*   rpg   = rowptr + (size_t)g * n0;   // per-graph rowptr window
        const float* disg  = dis + (size_t)g * n0;      // per-graph dis window
        float* outg = out + (size_t)g * n0 * D;

        // ---- 3 GCN layers ----
        for (int l = 0; l < 3; ++l) {
            const float* Ain = (l == 0) ? xin : Xf;
            k_gemm_mfma<<<g_gemm, threads, 0, stream>>>(Ain, wpack + (size_t)l * 32768,
                                                        nullptr, H, n0, 0, 0);
            k_csr_agg2<<<g_agg, threads, 0, stream>>>(H, rpg, csrsrc, disg, bl[l], Xf, n0, 1);
        }

        // ---- fc head ----
        k_gemm_mfma<<<g_gemm, threads, 0, stream>>>(Xf, wpack + (size_t)3 * 32768,
                                                    bf1, H, n0, 1, 1);
        k_gemm_mfma<<<g_gemm, threads, 0, stream>>>(H, wpack + (size_t)4 * 32768,
                                                    bf2, outg, n0, 1, 0);
    }
}

// Round 12
// 914.485 us; speedup vs baseline: 1.0507x; 1.0507x over previous
//
#include <hip/hip_runtime.h>
#include <hip/hip_bf16.h>

#define D 128

typedef __bf16 bf16x8 __attribute__((ext_vector_type(8)));
typedef float  f32x4  __attribute__((ext_vector_type(4)));

// ---------------- batched CSR build (both graphs; graph-1 node ids offset +n0) ----------------

// 4 edges per thread for MLP
__global__ void k_count_deg2(const int* __restrict__ ei, const int* __restrict__ eia,
                             int* __restrict__ deg, int e0, int e1, int n0) {
    int base = (blockIdx.x * blockDim.x + threadIdx.x) * 4;
    #pragma unroll
    for (int q = 0; q < 4; ++q) {
        int i = base + q;
        if (i < e0) atomicAdd(&deg[ei[e0 + i]], 1);
        else if (i < e0 + e1) { int k = i - e0; atomicAdd(&deg[eia[e1 + k] + n0], 1); }
    }
}

__global__ void k_dis(const int* __restrict__ deg, float* __restrict__ dis, int n) {
    int i = blockIdx.x * blockDim.x + threadIdx.x;
    if (i < n) dis[i] = rsqrtf((float)deg[i] + 1.0f);
}

__global__ __launch_bounds__(256) void k_scan1(const int* __restrict__ deg,
                                               int* __restrict__ rowptr,
                                               int* __restrict__ bsum, int n) {
    __shared__ int tmp[256];
    int t = threadIdx.x;
    int i = blockIdx.x * 256 + t;
    tmp[t] = (i < n) ? deg[i] : 0;
    __syncthreads();
    for (int ofs = 1; ofs < 256; ofs <<= 1) {
        int add = (t >= ofs) ? tmp[t - ofs] : 0;
        __syncthreads();
        tmp[t] += add;
        __syncthreads();
    }
    if (i < n) rowptr[i + 1] = tmp[t];
    if (t == 255) bsum[blockIdx.x] = tmp[255];
}

// single-block sequential-chunk scan (nb=391 here)
__global__ __launch_bounds__(256) void k_scan2(int* __restrict__ bsum, int nb) {
    __shared__ int tmp[256];
    int t = threadIdx.x;
    int carry = 0;
    for (int base = 0; base < nb; base += 256) {
        int idx = base + t;
        tmp[t] = (idx < nb) ? bsum[idx] : 0;
        __syncthreads();
        for (int ofs = 1; ofs < 256; ofs <<= 1) {
            int add = (t >= ofs) ? tmp[t - ofs] : 0;
            __syncthreads();
            tmp[t] += add;
            __syncthreads();
        }
        if (idx < nb) bsum[idx] = tmp[t] + carry;
        int total = tmp[255];
        __syncthreads();
        carry += total;
    }
}

// finalize rowptr and init cursor = rowptr (fused)
__global__ void k_scan3(int* __restrict__ rowptr, int* __restrict__ cursor,
                        const int* __restrict__ bsum, int n) {
    int i = blockIdx.x * blockDim.x + threadIdx.x;
    if (i == 0) { rowptr[0] = 0; cursor[0] = 0; }
    if (i < n) {
        int b = i >> 8;
        int val = rowptr[i + 1];
        if (b > 0) val += bsum[b - 1];
        rowptr[i + 1] = val;
        if (i + 1 < n) cursor[i + 1] = val;
    }
}

// scatter both graphs' edges; payload = raw per-graph src id; 4 edges/thread
__global__ void k_csr_fill2(const int* __restrict__ ei, const int* __restrict__ eia,
                            int* __restrict__ cursor, int* __restrict__ csr_src,
                            int e0, int e1, int n0) {
    int base = (blockIdx.x * blockDim.x + threadIdx.x) * 4;
    #pragma unroll
    for (int q = 0; q < 4; ++q) {
        int i = base + q;
        int s, d;
        if (i < e0) { s = ei[i]; d = ei[e0 + i]; }
        else if (i < e0 + e1) { int k = i - e0; s = eia[k]; d = eia[e1 + k] + n0; }
        else continue;
        int pos = atomicAdd(&cursor[d], 1);
        csr_src[pos] = s;
    }
}

// pre-gather per-edge source normalization: csrw[pos] = dis[src_global]
// (coalesced read of csrsrc, L2-resident dis gather, coalesced write — no scatter)
__global__ void k_fill_w(const int* __restrict__ csr_src, const float* __restrict__ dis,
                         float* __restrict__ csrw, int e0, int et, int n0) {
    int i = blockIdx.x * blockDim.x + threadIdx.x;
    if (i < et) {
        int s = csr_src[i];
        csrw[i] = dis[i < e0 ? s : s + n0];
    }
}

// ---------------- weight packing: f32 W[128][128] -> per-lane MFMA frag order ----------------
// slot i = ((kb*8 + ct)*64 + lane)*8 + j  ->  W[kb*32 + (lane>>4)*8 + j][ct*16 + (lane&15)]

__global__ __launch_bounds__(256) void k_pack_w5(
    const float* __restrict__ w0, const float* __restrict__ w1,
    const float* __restrict__ w2, const float* __restrict__ w3,
    const float* __restrict__ w4, __bf16* __restrict__ out) {
    int q = blockIdx.x >> 6;
    const float* W = (q == 0) ? w0 : (q == 1) ? w1 : (q == 2) ? w2 : (q == 3) ? w3 : w4;
    int i = ((blockIdx.x & 63) << 8) | threadIdx.x;      // 0..16383
    int j    = i & 7;
    int lane = (i >> 3) & 63;
    int ct   = (i >> 9) & 7;
    int kb   = i >> 12;
    int k = kb * 32 + (lane >> 4) * 8 + j;
    int c = ct * 16 + (lane & 15);
    float w = W[k * D + c];
    __bf16 hi = (__bf16)w;
    __bf16 lo = (__bf16)(w - (float)hi);
    __bf16* dstp = out + (size_t)q * 32768;
    dstp[i] = hi;
    dstp[16384 + i] = lo;
}

// ---------------- split-bf16 MFMA GEMM: C[n,128] = A[n,128] @ W + (bias)(relu) ----------------

__global__ __launch_bounds__(256) void k_gemm_mfma(
    const float* __restrict__ A, const __bf16* __restrict__ Wp,
    const float* __restrict__ bias, float* __restrict__ C, int n,
    int fuse_bias, int fuse_relu) {
    __shared__ __bf16 Ws[32768];     // 64 KiB: hi | lo, frag-packed
    int t = threadIdx.x;
    for (int i = t * 8; i < 32768; i += 2048)
        *(float4*)&Ws[i] = *(const float4*)&Wp[i];

    int wv = t >> 6, lane = t & 63;
    int lrow = lane & 15, lhi = lane >> 4;
    int m0 = blockIdx.x * 64 + wv * 16;

    bf16x8 ahi[4], alo[4];
    int arow = m0 + lrow;
    const float* ap = A + (size_t)arow * D + lhi * 8;
    #pragma unroll
    for (int kb = 0; kb < 4; ++kb) {
        float av[8];
        if (arow < n) {
            float4 p0 = *(const float4*)(ap + kb * 32);
            float4 p1 = *(const float4*)(ap + kb * 32 + 4);
            av[0] = p0.x; av[1] = p0.y; av[2] = p0.z; av[3] = p0.w;
            av[4] = p1.x; av[5] = p1.y; av[6] = p1.z; av[7] = p1.w;
        } else {
            #pragma unroll
            for (int j = 0; j < 8; ++j) av[j] = 0.0f;
        }
        #pragma unroll
        for (int j = 0; j < 8; ++j) {
            __bf16 h = (__bf16)av[j];
            ahi[kb][j] = h;
            alo[kb][j] = (__bf16)(av[j] - (float)h);
        }
    }
    __syncthreads();

    f32x4 acc[8];
    f32x4 zz = {0.f, 0.f, 0.f, 0.f};
    #pragma unroll
    for (int i = 0; i < 8; ++i) acc[i] = zz;

    #pragma unroll
    for (int kb = 0; kb < 4; ++kb) {
        #pragma unroll
        for (int ct = 0; ct < 8; ++ct) {
            int off = ((kb * 8 + ct) * 64 + lane) * 8;
            bf16x8 bh = *(const bf16x8*)&Ws[off];
            bf16x8 bl = *(const bf16x8*)&Ws[16384 + off];
            acc[ct] = __builtin_amdgcn_mfma_f32_16x16x32_bf16(ahi[kb], bh, acc[ct], 0, 0, 0);
            acc[ct] = __builtin_amdgcn_mfma_f32_16x16x32_bf16(ahi[kb], bl, acc[ct], 0, 0, 0);
            acc[ct] = __builtin_amdgcn_mfma_f32_16x16x32_bf16(alo[kb], bh, acc[ct], 0, 0, 0);
        }
    }

    // C/D layout: col=lane&15, row=(lane>>4)*4+reg  [verified m89/m91]
    #pragma unroll
    for (int ct = 0; ct < 8; ++ct) {
        int col = ct * 16 + lrow;
        float bv = fuse_bias ? bias[col] : 0.0f;
        #pragma unroll
        for (int r = 0; r < 4; ++r) {
            int row = m0 + lhi * 4 + r;
            if (row < n) {
                float v = acc[ct][r] + bv;
                if (fuse_relu) v = fmaxf(v, 0.0f);
                C[(size_t)row * D + col] = v;
            }
        }
    }
}

// ---------------- GCN aggregation: 1 wave/node, 2 ch/lane, unroll 4, pre-gathered weights ----------------

__global__ __launch_bounds__(256) void k_csr_agg3(
    const float* __restrict__ H, const int* __restrict__ rowptr,
    const int* __restrict__ csr_src, const float* __restrict__ csrw,
    const float* __restrict__ dis, const float* __restrict__ bias,
    float* __restrict__ X, int n, int relu) {
    int wid = (blockIdx.x * 256 + threadIdx.x) >> 6;
    int lane = threadIdx.x & 63;
    int v = __builtin_amdgcn_readfirstlane(wid);   // wave-uniform -> SGPR
    if (v >= n) return;
    float dv = dis[v];
    const float* Hv = H + (size_t)v * D;
    float acc0 = Hv[lane] * dv * dv;
    float acc1 = Hv[lane + 64] * dv * dv;
    int beg = rowptr[v], end = rowptr[v + 1];
    int j = beg;
    for (; j + 4 <= end; j += 4) {
        int s0 = csr_src[j + 0], s1 = csr_src[j + 1];
        int s2 = csr_src[j + 2], s3 = csr_src[j + 3];
        float w0 = csrw[j + 0] * dv, w1 = csrw[j + 1] * dv;
        float w2 = csrw[j + 2] * dv, w3 = csrw[j + 3] * dv;
        const float* p0 = H + (size_t)s0 * D;
        const float* p1 = H + (size_t)s1 * D;
        const float* p2 = H + (size_t)s2 * D;
        const float* p3 = H + (size_t)s3 * D;
        float a0 = p0[lane], b0 = p0[lane + 64];
        float a1 = p1[lane], b1 = p1[lane + 64];
        float a2 = p2[lane], b2 = p2[lane + 64];
        float a3 = p3[lane], b3 = p3[lane + 64];
        acc0 = fmaf(a0, w0, acc0); acc1 = fmaf(b0, w0, acc1);
        acc0 = fmaf(a1, w1, acc0); acc1 = fmaf(b1, w1, acc1);
        acc0 = fmaf(a2, w2, acc0); acc1 = fmaf(b2, w2, acc1);
        acc0 = fmaf(a3, w3, acc0); acc1 = fmaf(b3, w3, acc1);
    }
    for (; j < end; ++j) {
        int s = csr_src[j];
        float w = csrw[j] * dv;
        const float* p = H + (size_t)s * D;
        acc0 = fmaf(p[lane], w, acc0);
        acc1 = fmaf(p[lane + 64], w, acc1);
    }
    acc0 += bias[lane];
    acc1 += bias[lane + 64];
    if (relu) { acc0 = fmaxf(acc0, 0.f); acc1 = fmaxf(acc1, 0.f); }
    X[(size_t)v * D + lane] = acc0;
    X[(size_t)v * D + lane + 64] = acc1;
}

// ---------------- launcher ----------------

extern "C" void kernel_launch(void* const* d_in, const int* in_sizes, int n_in,
                              void* d_out, int out_size, void* d_ws, size_t ws_size,
                              hipStream_t stream) {
    const float* x    = (const float*)d_in[0];
    const int*   ei   = (const int*)d_in[1];
    const float* xa   = (const float*)d_in[2];
    const int*   eia  = (const int*)d_in[3];
    const float* W_in = (const float*)d_in[4];
    const float* b_in = (const float*)d_in[5];
    const float* W_h  = (const float*)d_in[6];
    const float* b_h  = (const float*)d_in[7];
    const float* W_out= (const float*)d_in[8];
    const float* b_out= (const float*)d_in[9];
    const float* Wf1  = (const float*)d_in[10];
    const float* bf1  = (const float*)d_in[11];
    const float* Wf2  = (const float*)d_in[12];
    const float* bf2  = (const float*)d_in[13];

    const int n0 = in_sizes[0] / D;       // 50000
    const int e0 = in_sizes[1] / 2;       // 800000
    const int n1 = in_sizes[2] / D;
    const int e1 = in_sizes[3] / 2;
    const int nt = n0 + n1;               // 100000
    const int et = e0 + e1;               // 1.6M

    float* Xf     = (float*)d_ws;                  // [n0,128]
    float* H      = Xf + (size_t)n0 * D;           // [n0,128]
    float* dis    = H  + (size_t)n0 * D;           // [nt]
    int*   deg    = (int*)(dis + nt);              // [nt]
    int*   rowptr = deg + nt;                      // [nt+4]
    int*   cursor = rowptr + (nt + 4);             // [nt]
    int*   bsum   = cursor + nt;                   // [512]
    int*   csrsrc = bsum + 512;                    // [et]
    float* csrw   = (float*)(csrsrc + et);         // [et]
    __bf16* wpack = (__bf16*)(csrw + et);          // 5 * 32768 bf16

    float* out = (float*)d_out;

    const float* bl[3] = {b_in, b_h, b_out};

    const int threads = 256;
    const int g_nt   = (nt + threads - 1) / threads;          // 391
    const int g_et   = (et + threads - 1) / threads;          // 6250
    const int g_et4  = (et + threads * 4 - 1) / (threads * 4); // 1563
    const int g_gemm = (n0 + 63) / 64;                        // 782
    const int g_agg  = (n0 * 64 + threads - 1) / threads;     // 12500 (1 wave/node)
    const int nb     = g_nt;

    // pack all 5 weight matrices (hi/lo split, frag order)
    k_pack_w5<<<320, threads, 0, stream>>>(W_in, W_h, W_out, Wf1, Wf2, wpack);

    // ---- batched CSR build over both graphs ----
    hipMemsetAsync(deg, 0, (size_t)nt * sizeof(int), stream);
    k_count_deg2<<<g_et4, threads, 0, stream>>>(ei, eia, deg, e0, e1, n0);
    k_dis<<<g_nt, threads, 0, stream>>>(deg, dis, nt);
    k_scan1<<<g_nt, threads, 0, stream>>>(deg, rowptr, bsum, nt);
    k_scan2<<<1, threads, 0, stream>>>(bsum, nb);
    k_scan3<<<g_nt, threads, 0, stream>>>(rowptr, cursor, bsum, nt);
    k_csr_fill2<<<g_et4, threads, 0, stream>>>(ei, eia, cursor, csrsrc, e0, e1, n0);
    k_fill_w<<<g_et, threads, 0, stream>>>(csrsrc, dis, csrw, e0, et, n0);

    for (int g = 0; g < 2; ++g) {
        const float* xin   = g ? xa : x;
        const int*   rpg   = rowptr + (size_t)g * n0;   // per-graph rowptr window
        const float* disg  = dis + (size_t)g * n0;      // per-graph dis window
        float* outg = out + (size_t)g * n0 * D;

        // ---- 3 GCN layers ----
        for (int l = 0; l < 3; ++l) {
            const float* Ain = (l == 0) ? xin : Xf;
            k_gemm_mfma<<<g_gemm, threads, 0, stream>>>(Ain, wpack + (size_t)l * 32768,
                                                        nullptr, H, n0, 0, 0);
            k_csr_agg3<<<g_agg, threads, 0, stream>>>(H, rpg, csrsrc, csrw, disg,
                                                      bl[l], Xf, n0, 1);
        }

        // ---- fc head ----
        k_gemm_mfma<<<g_gemm, threads, 0, stream>>>(Xf, wpack + (size_t)3 * 32768,
                                                    bf1, H, n0, 1, 1);
        k_gemm_mfma<<<g_gemm, threads, 0, stream>>>(H, wpack + (size_t)4 * 32768,
                                                    bf2, outg, n0, 1, 0);
    }
}